// Round 7
// baseline (304.127 us; speedup 1.0000x reference)
//
#include <hip/hip_runtime.h>
#include <hip/hip_bf16.h>

// out[b,o] = sum_{i,n} T_n(x[b,i]) * w[o,i,n]
// DIAGNOSTIC ROUND: real kernel = round-6 verbatim (passed, 32.2 us).
// Added 3 repetition-amplified probe kernels (keep-alive, no stores) sized to
// beat the ~41 us fill dispatches into rocprof top-5, decomposing the 32 us:
//   probe_stage x12: global->LDS x staging only
//   probe_comp  x5 : inner loop w/ real bfrag L2 stream (no stage)
//   probe_chain x6 : inner loop w/ single cached bfrag (no L2 stream)

typedef __attribute__((ext_vector_type(8)))  short bf16x8;
typedef __attribute__((ext_vector_type(16))) float f32x16;
typedef __attribute__((ext_vector_type(4)))  float f32x4;

__device__ __forceinline__ short f2b(float f) {
    __hip_bfloat16 h = __float2bfloat16(f);
    short s;
    __builtin_memcpy(&s, &h, sizeof(s));
    return s;
}

__device__ __forceinline__ unsigned pkbf(float lo, float hi) {
    __hip_bfloat162 h2 = __float22bfloat162_rn(make_float2(lo, hi));
    unsigned u;
    __builtin_memcpy(&u, &h2, 4);
    return u;
}

// Pack w [32][256][8] fp32 -> wB[kc2][lane][jj] bf16 in B-fragment order:
//   o = lane&31, g = lane>>5, i = 2*kc2 + (jj>>2), n = 4*g + (jj&3)
__global__ __launch_bounds__(256) void prep_w_kernel(const float* __restrict__ w,
                                                     short* __restrict__ wB) {
    int idx = blockIdx.x * 256 + threadIdx.x;     // 0..65535
    int kc2 = idx >> 9;
    int l   = (idx >> 3) & 63;
    int jj  = idx & 7;
    int o = l & 31, g = l >> 5;
    int i = 2 * kc2 + (jj >> 2);
    int n = 4 * g + (jj & 3);
    wB[idx] = f2b(w[(o * 256 + i) * 8 + n]);
}

// ---------------- real kernel: round-6 verbatim (PASSED, 32.2 us) ----------
__global__ __launch_bounds__(256, 5) void cheb_mm_kernel(const float* __restrict__ x,
                                                         const short* __restrict__ wB,
                                                         float* __restrict__ out) {
    __shared__ float smem[8192];
    const int tid = threadIdx.x;
    const int wv  = tid >> 6;
    const int l   = tid & 63;
    const int g   = l >> 5;
    const int r0  = l & 31;
    const long long rowB = (long long)blockIdx.x * 32;

    {
        const float4* xg4 = (const float4*)(x + rowB * 256);
        float4 stg[8];
        #pragma unroll
        for (int q = 0; q < 8; ++q)
            stg[q] = xg4[q * 256 + tid];
        float2* s2 = (float2*)smem;
        #pragma unroll
        for (int q = 0; q < 8; ++q) {
            int slot = q * 256 + tid;
            int row = slot >> 6, f4 = slot & 63;
            int p0 = 2 * f4, p1 = 2 * f4 + 1;
            int d0 = (p0 & ~31) + ((p0 & 31) ^ (row & 31));
            int d1 = (p1 & ~31) + ((p1 & 31) ^ (row & 31));
            s2[row * 128 + d0] = make_float2(stg[q].x, stg[q].y);
            s2[row * 128 + d1] = make_float2(stg[q].z, stg[q].w);
        }
    }
    __syncthreads();

    f32x16 accA{}, accB{};
    const bf16x8* wq = (const bf16x8*)wB + wv * 2048 + l;
    const float* sf = smem;
    const int xbase = r0 * 256 + wv * 64 + g;

#if __has_builtin(__builtin_amdgcn_permlane32_swap)
    bf16x8 bfc[4];
    float  xc[2];
    #pragma unroll
    for (int p = 0; p < 4; ++p) bfc[p] = wq[p * 64];
    xc[0] = sf[xbase + ((0 ^ r0) << 1)];
    xc[1] = sf[xbase + ((1 ^ r0) << 1)];

    #pragma unroll
    for (int t = 0; t < 32; ++t) {
        const bf16x8 bfrag = bfc[t & 3];
        const float  xv    = xc[t & 1];
        if (t + 4 < 32) bfc[t & 3] = wq[(t + 4) * 64];
        if (t + 2 < 32) xc[t & 1] = sf[xbase + (((t + 2) ^ r0) << 1)];

        const float x2 = xv + xv;
        const float T2 = fmaf(x2, xv, -1.f);
        const float T3 = fmaf(x2, T2, -xv);
        const float T4 = fmaf(x2, T3, -T2);
        const float T5 = fmaf(x2, T4, -T3);
        const float T6 = fmaf(x2, T5, -T4);
        const float T7 = fmaf(x2, T6, -T5);
        unsigned R0 = pkbf(1.f, xv);
        unsigned R1 = pkbf(T2, T3);
        unsigned R2 = pkbf(T4, T5);
        unsigned R3 = pkbf(T6, T7);
        auto r02 = __builtin_amdgcn_permlane32_swap(R0, R2, false, false);
        auto r13 = __builtin_amdgcn_permlane32_swap(R1, R3, false, false);
        union { unsigned u[4]; bf16x8 v; } af;
        af.u[0] = r02[0]; af.u[1] = r13[0];
        af.u[2] = r02[1]; af.u[3] = r13[1];
        if (t & 1)
            accB = __builtin_amdgcn_mfma_f32_32x32x16_bf16(af.v, bfrag, accB, 0, 0, 0);
        else
            accA = __builtin_amdgcn_mfma_f32_32x32x16_bf16(af.v, bfrag, accA, 0, 0, 0);
    }
#else
    const float2* srow = (const float2*)smem + r0 * 128 + wv * 32;
    #pragma unroll 8
    for (int t = 0; t < 32; ++t) {
        const bf16x8 bfrag = wq[t * 64];
        const float2 xv = srow[t ^ r0];
        const float xa = xv.x, xb = xv.y;
        const float x2a = xa + xa, x2b = xb + xb;
        const float a2 = x2a * xa - 1.f;
        const float a3 = x2a * a2 - xa;
        const float a4 = x2a * a3 - a2;
        const float a5 = x2a * a4 - a3;
        const float b2 = x2b * xb - 1.f;
        const float b3 = x2b * b2 - xb;
        const float b4 = x2b * b3 - b2;
        const float b5 = x2b * b4 - b3;
        const float ua0 = g ? a4 : 1.f;
        const float ua1 = g ? a5 : xa;
        const float ua2 = x2a * ua1 - ua0;
        const float ua3 = x2a * ua2 - ua1;
        const float ub0 = g ? b4 : 1.f;
        const float ub1 = g ? b5 : xb;
        const float ub2 = x2b * ub1 - ub0;
        const float ub3 = x2b * ub2 - ub1;
        bf16x8 afrag;
        afrag[0] = f2b(ua0); afrag[1] = f2b(ua1);
        afrag[2] = f2b(ua2); afrag[3] = f2b(ua3);
        afrag[4] = f2b(ub0); afrag[5] = f2b(ub1);
        afrag[6] = f2b(ub2); afrag[7] = f2b(ub3);
        if (t & 1)
            accB = __builtin_amdgcn_mfma_f32_32x32x16_bf16(afrag, bfrag, accB, 0, 0, 0);
        else
            accA = __builtin_amdgcn_mfma_f32_32x32x16_bf16(afrag, bfrag, accA, 0, 0, 0);
    }
#endif
    const f32x16 acc = accA + accB;

    __syncthreads();
    #pragma unroll
    for (int r = 0; r < 16; ++r) {
        const int rloc = (r & 3) + 8 * (r >> 2) + 4 * g;
        smem[wv * 1024 + rloc * 32 + r0] = acc[r];
    }
    __syncthreads();

    {
        float* op = out + rowB * 32;
        const int f = tid * 4;
        f32x4 v0 = *(const f32x4*)&smem[f];
        f32x4 v1 = *(const f32x4*)&smem[1024 + f];
        f32x4 v2 = *(const f32x4*)&smem[2048 + f];
        f32x4 v3 = *(const f32x4*)&smem[3072 + f];
        f32x4 s = (v0 + v1) + (v2 + v3);
        *(f32x4*)(op + f) = s;
    }
}

// ---------------- probe A: stage-only, x12 reps, distinct tiles ------------
__global__ __launch_bounds__(256, 5) void probe_stage(const float* __restrict__ x) {
    __shared__ float smem[8192];
    const int tid = threadIdx.x;
    for (int p = 0; p < 12; ++p) {
        const unsigned bid = (blockIdx.x + (unsigned)p * 997u) & 2047u;
        const float4* xg4 = (const float4*)(x + (long long)bid * 8192);
        float4 stg[8];
        #pragma unroll
        for (int q = 0; q < 8; ++q) stg[q] = xg4[q * 256 + tid];
        float2* s2 = (float2*)smem;
        #pragma unroll
        for (int q = 0; q < 8; ++q) {
            int slot = q * 256 + tid;
            int row = slot >> 6, f4 = slot & 63;
            int p0 = 2 * f4, p1 = 2 * f4 + 1;
            int d0 = (p0 & ~31) + ((p0 & 31) ^ (row & 31));
            int d1 = (p1 & ~31) + ((p1 & 31) ^ (row & 31));
            s2[row * 128 + d0] = make_float2(stg[q].x, stg[q].y);
            s2[row * 128 + d1] = make_float2(stg[q].z, stg[q].w);
        }
        __syncthreads();
        float v = smem[(tid * 33) & 8191];          // keeps all writes+loads live
        asm volatile("" :: "v"(v));
        __syncthreads();
    }
}

// ---------------- probe B: compute w/ real bfrag stream, x5 reps -----------
__global__ __launch_bounds__(256, 5) void probe_comp(const short* __restrict__ wB) {
    __shared__ float smem[8192];
    const int tid = threadIdx.x;
    const int wv = tid >> 6, l = tid & 63, g = l >> 5, r0 = l & 31;
    #pragma unroll
    for (int k = 0; k < 32; ++k)                    // finite junk x-values
        smem[k * 256 + tid] = (float)((tid + k) & 31) * 0.03f - 0.45f;
    __syncthreads();
    int off = 0;
    asm volatile("" : "+v"(off));                   // opaque 0: defeats LICM/CSE
    f32x16 accA{}, accB{};
    const float* sf = smem;
    const int xbase = r0 * 256 + wv * 64 + g;
    for (int p = 0; p < 5; ++p) {
        const bf16x8* wq = (const bf16x8*)wB + wv * 2048 + l + off;
        bf16x8 bfc[4];
        float  xc[2];
        #pragma unroll
        for (int q = 0; q < 4; ++q) bfc[q] = wq[q * 64];
        xc[0] = sf[xbase + ((0 ^ r0) << 1) + off];
        xc[1] = sf[xbase + ((1 ^ r0) << 1) + off];
        #pragma unroll
        for (int t = 0; t < 32; ++t) {
            const bf16x8 bfrag = bfc[t & 3];
            const float  xv    = xc[t & 1];
            if (t + 4 < 32) bfc[t & 3] = wq[(t + 4) * 64];
            if (t + 2 < 32) xc[t & 1] = sf[xbase + (((t + 2) ^ r0) << 1) + off];
            const float x2 = xv + xv;
            const float T2 = fmaf(x2, xv, -1.f);
            const float T3 = fmaf(x2, T2, -xv);
            const float T4 = fmaf(x2, T3, -T2);
            const float T5 = fmaf(x2, T4, -T3);
            const float T6 = fmaf(x2, T5, -T4);
            const float T7 = fmaf(x2, T6, -T5);
            unsigned R0 = pkbf(1.f, xv);
            unsigned R1 = pkbf(T2, T3);
            unsigned R2 = pkbf(T4, T5);
            unsigned R3 = pkbf(T6, T7);
#if __has_builtin(__builtin_amdgcn_permlane32_swap)
            auto r02 = __builtin_amdgcn_permlane32_swap(R0, R2, false, false);
            auto r13 = __builtin_amdgcn_permlane32_swap(R1, R3, false, false);
            union { unsigned u[4]; bf16x8 v; } af;
            af.u[0] = r02[0]; af.u[1] = r13[0];
            af.u[2] = r02[1]; af.u[3] = r13[1];
#else
            union { unsigned u[4]; bf16x8 v; } af;
            af.u[0] = R0; af.u[1] = R1; af.u[2] = R2; af.u[3] = R3;
#endif
            if (t & 1)
                accB = __builtin_amdgcn_mfma_f32_32x32x16_bf16(af.v, bfrag, accB, 0, 0, 0);
            else
                accA = __builtin_amdgcn_mfma_f32_32x32x16_bf16(af.v, bfrag, accA, 0, 0, 0);
        }
        asm volatile("" : "+v"(off));
    }
    #pragma unroll
    for (int r = 0; r < 16; ++r) {
        asm volatile("" :: "v"(accA[r]));
        asm volatile("" :: "v"(accB[r]));
    }
}

// ---------------- probe C: compute w/ SINGLE cached bfrag, x6 reps ---------
__global__ __launch_bounds__(256, 5) void probe_chain(const short* __restrict__ wB) {
    __shared__ float smem[8192];
    const int tid = threadIdx.x;
    const int wv = tid >> 6, l = tid & 63, g = l >> 5, r0 = l & 31;
    #pragma unroll
    for (int k = 0; k < 32; ++k)
        smem[k * 256 + tid] = (float)((tid + k) & 31) * 0.03f - 0.45f;
    __syncthreads();
    int off = 0;
    asm volatile("" : "+v"(off));
    f32x16 accA{}, accB{};
    const float* sf = smem;
    const int xbase = r0 * 256 + wv * 64 + g;
    const bf16x8 bfix = ((const bf16x8*)wB)[wv * 2048 + l];   // loaded ONCE
    for (int p = 0; p < 6; ++p) {
        #pragma unroll
        for (int t = 0; t < 32; ++t) {
            const float xv = sf[xbase + ((t ^ r0) << 1) + off];
            const float x2 = xv + xv;
            const float T2 = fmaf(x2, xv, -1.f);
            const float T3 = fmaf(x2, T2, -xv);
            const float T4 = fmaf(x2, T3, -T2);
            const float T5 = fmaf(x2, T4, -T3);
            const float T6 = fmaf(x2, T5, -T4);
            const float T7 = fmaf(x2, T6, -T5);
            unsigned R0 = pkbf(1.f, xv);
            unsigned R1 = pkbf(T2, T3);
            unsigned R2 = pkbf(T4, T5);
            unsigned R3 = pkbf(T6, T7);
#if __has_builtin(__builtin_amdgcn_permlane32_swap)
            auto r02 = __builtin_amdgcn_permlane32_swap(R0, R2, false, false);
            auto r13 = __builtin_amdgcn_permlane32_swap(R1, R3, false, false);
            union { unsigned u[4]; bf16x8 v; } af;
            af.u[0] = r02[0]; af.u[1] = r13[0];
            af.u[2] = r02[1]; af.u[3] = r13[1];
#else
            union { unsigned u[4]; bf16x8 v; } af;
            af.u[0] = R0; af.u[1] = R1; af.u[2] = R2; af.u[3] = R3;
#endif
            if (t & 1)
                accB = __builtin_amdgcn_mfma_f32_32x32x16_bf16(af.v, bfix, accB, 0, 0, 0);
            else
                accA = __builtin_amdgcn_mfma_f32_32x32x16_bf16(af.v, bfix, accA, 0, 0, 0);
        }
        asm volatile("" : "+v"(off));
    }
    #pragma unroll
    for (int r = 0; r < 16; ++r) {
        asm volatile("" :: "v"(accA[r]));
        asm volatile("" :: "v"(accB[r]));
    }
}

extern "C" void kernel_launch(void* const* d_in, const int* in_sizes, int n_in,
                              void* d_out, int out_size, void* d_ws, size_t ws_size,
                              hipStream_t stream) {
    const float* x = (const float*)d_in[0];   // [65536, 256] fp32
    const float* w = (const float*)d_in[1];   // [32, 256, 8] fp32
    float* out = (float*)d_out;               // [65536, 32] fp32
    short* wB = (short*)d_ws;                 // 128 KB bf16 packed weights

    prep_w_kernel<<<256, 256, 0, stream>>>(w, wB);
    cheb_mm_kernel<<<2048, 256, 0, stream>>>(x, wB, out);
    // diagnostic probes (read-only, keep-alive, no stores; amplify into top-5)
    probe_stage<<<2048, 256, 0, stream>>>(x);
    probe_comp<<<2048, 256, 0, stream>>>(wB);
    probe_chain<<<2048, 256, 0, stream>>>(wB);
}

// Round 8
// 31.051 us; speedup vs baseline: 9.7944x; 9.7944x over previous
//
#include <hip/hip_runtime.h>
#include <hip/hip_bf16.h>

// out[b,o] = sum_{i,n} T_n(x[b,i]) * w[o,i,n]
// GEMM view: M=B=65536, N=O=32, K=I*8=2048. MFMA v_mfma_f32_32x32x16_bf16.
// Round-8: barrier-free wave-private staging.
//   Wave wv's K-quarter (kc2 in [wv*32,wv*32+32)) touches ONLY x float-columns
//   [wv*64, wv*64+64) of the 32-row tile -> disjoint 8 KB slices. Each wave
//   stages its own slice (global->reg->LDS, proven XOR swizzle) and computes
//   with NO __syncthreads; partials overwrite the wave's own dead slice; one
//   barrier total before the cross-wave reduce. Breaks the stage/compute
//   phase-lock that made round 2/4/6 all land at ~32 us (probe: stage=10 us
//   at BW ceiling, compute~13 us, serialized).

typedef __attribute__((ext_vector_type(8)))  short bf16x8;
typedef __attribute__((ext_vector_type(16))) float f32x16;
typedef __attribute__((ext_vector_type(4)))  float f32x4;

__device__ __forceinline__ short f2b(float f) {
    __hip_bfloat16 h = __float2bfloat16(f);
    short s;
    __builtin_memcpy(&s, &h, sizeof(s));
    return s;
}

__device__ __forceinline__ unsigned pkbf(float lo, float hi) {
    __hip_bfloat162 h2 = __float22bfloat162_rn(make_float2(lo, hi));
    unsigned u;
    __builtin_memcpy(&u, &h2, 4);
    return u;
}

// Pack w [32][256][8] fp32 -> wB[kc2][lane][jj] bf16 in B-fragment order:
//   o = lane&31, g = lane>>5, i = 2*kc2 + (jj>>2), n = 4*g + (jj&3)
// (HW-verified: rounds 2-7 passed with this layout, absmax 1.95e-3)
__global__ __launch_bounds__(256) void prep_w_kernel(const float* __restrict__ w,
                                                     short* __restrict__ wB) {
    int idx = blockIdx.x * 256 + threadIdx.x;     // 0..65535
    int kc2 = idx >> 9;
    int l   = (idx >> 3) & 63;
    int jj  = idx & 7;
    int o = l & 31, g = l >> 5;
    int i = 2 * kc2 + (jj >> 2);
    int n = 4 * g + (jj & 3);
    wB[idx] = f2b(w[(o * 256 + i) * 8 + n]);
}

__global__ __launch_bounds__(256, 5) void cheb_mm_kernel(const float* __restrict__ x,
                                                         const short* __restrict__ wB,
                                                         float* __restrict__ out) {
    __shared__ float smem[8192];                  // 32 KB: x tile, then partials
    const int tid = threadIdx.x;
    const int wv  = tid >> 6;                     // K-quarter / column-slice
    const int l   = tid & 63;
    const int g   = l >> 5;                       // i-parity this lane computes
    const int r0  = l & 31;                       // batch row in tile / o column
    const long long rowB = (long long)blockIdx.x * 32;

    const bf16x8* wq = (const bf16x8*)wB + wv * 2048 + l;
    // early B prefetch: issue before staging so it flies under the x wait
    bf16x8 bfc[4];
    #pragma unroll
    for (int p = 0; p < 4; ++p) bfc[p] = wq[p * 64];

    // ---- wave-private stage: rows 0..31, float cols [wv*64, wv*64+64) ----
    // NO barrier: this wave is the only reader of this slice.
    {
        const float4* xg4 = (const float4*)(x + rowB * 256);
        const int f4l = l & 15;                   // 16 float4 per row-slice
        const int rsub = l >> 4;                  // 4 rows per pass
        float4 stg[8];
        #pragma unroll
        for (int q = 0; q < 8; ++q)
            stg[q] = xg4[(q * 4 + rsub) * 64 + wv * 16 + f4l];   // all in flight
        #pragma unroll
        for (int q = 0; q < 8; ++q) {
            const int row  = q * 4 + rsub;
            const int base = row * 256 + wv * 64; // dword base of slice row
            const int s    = row & 31;
            const int p0 = 2 * f4l, p1 = 2 * f4l + 1;   // local f2 idx 0..31
            *(float2*)&smem[base + 2 * (p0 ^ s)] = make_float2(stg[q].x, stg[q].y);
            *(float2*)&smem[base + 2 * (p1 ^ s)] = make_float2(stg[q].z, stg[q].w);
        }
    }

    // ---- compute: kc2 = wv*32+t, t=0..31 (round-6 proven body) ----
    f32x16 accA{}, accB{};
    const float* sf = smem;
    const int xbase = r0 * 256 + wv * 64 + g;     // + 2*(t^r0) per iter

    float xc[2];
    xc[0] = sf[xbase + ((0 ^ r0) << 1)];
    xc[1] = sf[xbase + ((1 ^ r0) << 1)];

    #pragma unroll
    for (int t = 0; t < 32; ++t) {
        const bf16x8 bfrag = bfc[t & 3];
        const float  xv    = xc[t & 1];
        if (t + 4 < 32) bfc[t & 3] = wq[(t + 4) * 64];
        if (t + 2 < 32) xc[t & 1] = sf[xbase + (((t + 2) ^ r0) << 1)];

        const float x2 = xv + xv;
        const float T2 = fmaf(x2, xv, -1.f);
        const float T3 = fmaf(x2, T2, -xv);
        const float T4 = fmaf(x2, T3, -T2);
        const float T5 = fmaf(x2, T4, -T3);
        const float T6 = fmaf(x2, T5, -T4);
        const float T7 = fmaf(x2, T6, -T5);
        unsigned R0 = pkbf(1.f, xv);
        unsigned R1 = pkbf(T2, T3);
        unsigned R2 = pkbf(T4, T5);
        unsigned R3 = pkbf(T6, T7);
        // hazard-safe builtin; round-6 HW-verified wiring
        auto r02 = __builtin_amdgcn_permlane32_swap(R0, R2, false, false);
        auto r13 = __builtin_amdgcn_permlane32_swap(R1, R3, false, false);
        union { unsigned u[4]; bf16x8 v; } af;
        af.u[0] = r02[0]; af.u[1] = r13[0];
        af.u[2] = r02[1]; af.u[3] = r13[1];
        if (t & 1)
            accB = __builtin_amdgcn_mfma_f32_32x32x16_bf16(af.v, bfrag, accB, 0, 0, 0);
        else
            accA = __builtin_amdgcn_mfma_f32_32x32x16_bf16(af.v, bfrag, accA, 0, 0, 0);
    }
    const f32x16 acc = accA + accB;

    // ---- partials into this wave's own (dead) slice: no barrier needed ----
    // value for (row rloc, o=r0) at smem[rloc*256 + wv*64 + r0]
    #pragma unroll
    for (int r = 0; r < 16; ++r) {
        const int rloc = (r & 3) + 8 * (r >> 2) + 4 * g;   // C/D row (HW-verified)
        smem[rloc * 256 + wv * 64 + r0] = acc[r];
    }
    __syncthreads();                              // the block's ONLY barrier

    // ---- cross-wave reduce + coalesced f32x4 store of out[32][32] ----
    {
        float* op = out + rowB * 32;
        const int f   = tid * 4;                  // 1024 floats / 256 thr
        const int row = f >> 5;
        const int c   = f & 31;
        const int b   = row * 256 + c;
        f32x4 v0 = *(const f32x4*)&smem[b];
        f32x4 v1 = *(const f32x4*)&smem[b + 64];
        f32x4 v2 = *(const f32x4*)&smem[b + 128];
        f32x4 v3 = *(const f32x4*)&smem[b + 192];
        f32x4 s = (v0 + v1) + (v2 + v3);
        *(f32x4*)(op + f) = s;
    }
}

extern "C" void kernel_launch(void* const* d_in, const int* in_sizes, int n_in,
                              void* d_out, int out_size, void* d_ws, size_t ws_size,
                              hipStream_t stream) {
    const float* x = (const float*)d_in[0];   // [65536, 256] fp32
    const float* w = (const float*)d_in[1];   // [32, 256, 8] fp32
    float* out = (float*)d_out;               // [65536, 32] fp32
    short* wB = (short*)d_ws;                 // 128 KB bf16 packed weights

    prep_w_kernel<<<256, 256, 0, stream>>>(w, wB);
    cheb_mm_kernel<<<2048, 256, 0, stream>>>(x, wB, out);
}